// Round 2
// baseline (243.423 us; speedup 1.0000x reference)
//
#include <hip/hip_runtime.h>

#define ETA_MIN 2.302585092994046f  // log(10)
#define ETA_MAX 20.0f

// Native clang vector type — HIP's float4 struct is rejected by
// __builtin_nontemporal_load/store; ext_vector_type(4) float is accepted.
typedef float v4f __attribute__((ext_vector_type(4)));

constexpr int BLOCK  = 256;
constexpr int UNROLL = 8;   // 8 independent 16B loads in flight per lane

// Elementwise: w_i = (loss_i > eta) ? 0 : 1 - loss_i/eta,
// eta = clamp(eta_value[0], ETA_MIN, ETA_MAX).
// Memory-bound: 256 MB total traffic, roofline ~41 us at 6.3 TB/s.
// Round-2 structure: each block owns ONE contiguous 32 KB chunk
// (BLOCK*UNROLL v4f). Thread t handles chunk + t + u*BLOCK, so every wave
// access is 1 KB coalesced AND the block's 8 loads / 8 stores walk two
// sequential streams (DRAM page locality — the round-1 version strided its
// unroll by 8 MB and was neutral). 8 outstanding nontemporal loads per lane
// for latency hiding; one-shot blocks, no grid-stride loop.
__global__ __launch_bounds__(BLOCK) void Weightfun_78374563217418_kernel(
    const v4f* __restrict__ loss, const float* __restrict__ eta_ptr,
    v4f* __restrict__ out, int n4) {
    // uniform scalar broadcast load; clamped per reference
    float eta = fminf(fmaxf(eta_ptr[0], ETA_MIN), ETA_MAX);
    float inv_eta = 1.0f / eta;  // one precise divide per thread

    const int base = (int)blockIdx.x * (BLOCK * UNROLL) + (int)threadIdx.x;

    v4f l[UNROLL];
    // Phase 1: issue all loads (independent -> 8 in flight per lane)
#pragma unroll
    for (int u = 0; u < UNROLL; ++u) {
        int idx = base + u * BLOCK;
        if (idx < n4) l[u] = __builtin_nontemporal_load(&loss[idx]);
    }
    // Phase 2: compute + store as each load drains (compiler emits
    // per-use s_waitcnt vmcnt(N), not a full drain)
#pragma unroll
    for (int u = 0; u < UNROLL; ++u) {
        int idx = base + u * BLOCK;
        if (idx < n4) {
            v4f v = l[u];
            v4f w;
            w.x = (v.x > eta) ? 0.0f : fmaf(-v.x, inv_eta, 1.0f);
            w.y = (v.y > eta) ? 0.0f : fmaf(-v.y, inv_eta, 1.0f);
            w.z = (v.z > eta) ? 0.0f : fmaf(-v.z, inv_eta, 1.0f);
            w.w = (v.w > eta) ? 0.0f : fmaf(-v.w, inv_eta, 1.0f);
            __builtin_nontemporal_store(w, &out[idx]);
        }
    }
}

extern "C" void kernel_launch(void* const* d_in, const int* in_sizes, int n_in,
                              void* d_out, int out_size, void* d_ws, size_t ws_size,
                              hipStream_t stream) {
    const v4f*   loss = (const v4f*)d_in[0];
    const float* eta  = (const float*)d_in[1];
    v4f*         out  = (v4f*)d_out;

    int n  = in_sizes[0];   // 33554432 = 2^25, divisible by 4
    int n4 = n / 4;         // 8388608 v4f elements

    int per_block = BLOCK * UNROLL;              // 2048 v4f = 32 KB
    int grid = (n4 + per_block - 1) / per_block; // 4096 blocks = 16/CU

    Weightfun_78374563217418_kernel<<<grid, BLOCK, 0, stream>>>(loss, eta, out, n4);
}

// Round 3
// 218.930 us; speedup vs baseline: 1.1119x; 1.1119x over previous
//
#include <hip/hip_runtime.h>
#include <hip/hip_bf16.h>

#define ETA_MIN 2.302585092994046f  // log(10)
#define ETA_MAX 20.0f

// Native clang vector type — HIP's float4 is a struct and is rejected by
// __builtin_nontemporal_load/store; ext_vector_type(4) float is accepted.
typedef float v4f __attribute__((ext_vector_type(4)));

// Elementwise: w_i = (loss_i > eta) ? 0 : 1 - loss_i/eta, eta = clamp(eta_value[0], ETA_MIN, ETA_MAX)
// Memory-bound: 256 MB total traffic, roofline ~41 us at 6.3 TB/s achievable.
//
// EMPIRICAL NOTE (rounds 0-2): this one-load-one-store, short-lived-wave
// structure is the measured optimum (~218.6 us total). Per-wave load batching
// regressed it: UNROLL=4 grid-strided -> +8 us; UNROLL=8 contiguous 32KB
// chunks -> +25 us. At 8 VGPR / full occupancy, CU-level MLP (32 waves x 1
// load) + instant wave retire beats wave-level MLP, which concentrates each
// wave's in-order vmcnt chain on a narrow address window. Do not re-add
// batching without a within-probe A/B.
__global__ void Weightfun_78374563217418_kernel(const v4f* __restrict__ loss,
                                                const float* __restrict__ eta_ptr,
                                                v4f* __restrict__ out,
                                                int n4) {
    int i = blockIdx.x * blockDim.x + threadIdx.x;
    // scalar broadcast load; clamped per reference
    float eta = eta_ptr[0];
    eta = fminf(fmaxf(eta, ETA_MIN), ETA_MAX);
    float inv_eta = 1.0f / eta;  // one precise divide per thread

    if (i < n4) {
        v4f l = __builtin_nontemporal_load(&loss[i]);
        v4f w;
        w.x = (l.x > eta) ? 0.0f : fmaf(-l.x, inv_eta, 1.0f);
        w.y = (l.y > eta) ? 0.0f : fmaf(-l.y, inv_eta, 1.0f);
        w.z = (l.z > eta) ? 0.0f : fmaf(-l.z, inv_eta, 1.0f);
        w.w = (l.w > eta) ? 0.0f : fmaf(-l.w, inv_eta, 1.0f);
        __builtin_nontemporal_store(w, &out[i]);
    }
}

extern "C" void kernel_launch(void* const* d_in, const int* in_sizes, int n_in,
                              void* d_out, int out_size, void* d_ws, size_t ws_size,
                              hipStream_t stream) {
    const v4f*   loss = (const v4f*)d_in[0];
    const float* eta  = (const float*)d_in[1];
    v4f*         out  = (v4f*)d_out;

    int n  = in_sizes[0];          // 33554432 = 2^25, divisible by 4
    int n4 = n / 4;                // 8388608
    int block = 256;
    int grid  = (n4 + block - 1) / block;  // 32768 — saturates 256 CUs

    Weightfun_78374563217418_kernel<<<grid, block, 0, stream>>>(loss, eta, out, n4);
}